// Round 5
// baseline (751.169 us; speedup 1.0000x reference)
//
#include <hip/hip_runtime.h>
#include <cstdint>
#include <cstddef>

// ---------------------------------------------------------------------------
// CCA-SSG forward: 2-layer GraphConv (norm='both') x 2 graphs + column z-score
// Round 5: (1) histogram w/ packed-u16 LDS counters -> 40KB LDS, 4 blk/CU;
// (2) unified CSR build across both graphs (scan over 2M, fill over 2E);
// (3) layer-2 gather fused with column-stats (non-atomic block partials).
// ---------------------------------------------------------------------------

#define SCAN_CHUNK 1024
#define HCHUNK 20000       // nodes per histogram chunk (packed u16 -> 40 KB LDS)
#define HHALF  (HCHUNK/2)
#define HSLICES 16         // edge slices per (array, chunk)

typedef __attribute__((ext_vector_type(8))) short bf16x8;
typedef __attribute__((ext_vector_type(4))) float f32x4;

__device__ __forceinline__ unsigned short f2bf(float f) {
    unsigned int u = __float_as_uint(f);
    unsigned int r = (u + 0x7FFFu + ((u >> 16) & 1u)) >> 16;   // RNE
    return (unsigned short)r;
}
__device__ __forceinline__ float bflo(unsigned int u) { return __uint_as_float(u << 16); }
__device__ __forceinline__ float bfhi(unsigned int u) { return __uint_as_float(u & 0xffff0000u); }

// ---- binned degree histogram: packed u16 LDS counters, no global atomics --
// block = (array a, chunk c, slice s). Two nodes share one u32 (max per-node
// count ~40 << 65536, so halves never carry).
__global__ __launch_bounds__(256) void hist_kernel(
    const int* __restrict__ src1, const int* __restrict__ dst1,
    const int* __restrict__ src2, const int* __restrict__ dst2,
    unsigned int* __restrict__ part, int E, int nchunks)
{
    __shared__ unsigned int h[HHALF];
    const int bid = blockIdx.x;
    const int a = bid / (nchunks * HSLICES);
    const int r = bid % (nchunks * HSLICES);
    const int c = r / HSLICES, s = r % HSLICES;
    const int* idx = a == 0 ? src1 : a == 1 ? dst1 : a == 2 ? src2 : dst2;

    for (int i = threadIdx.x; i < HHALF; i += 256) h[i] = 0;
    __syncthreads();

    const int base = c * HCHUNK;
    const int lo = (int)((long long)s * E / HSLICES);
    const int hi = (int)((long long)(s + 1) * E / HSLICES);
    for (int i = lo + threadIdx.x; i < hi; i += 256) {
        unsigned int v = (unsigned int)(idx[i] - base);
        if (v < HCHUNK) atomicAdd(&h[v >> 1], 1u << ((v & 1u) << 4));
    }
    __syncthreads();

    unsigned int* out = part + (size_t)bid * HHALF;
    for (int i = threadIdx.x; i < HHALF; i += 256) out[i] = h[i];
}

// deg layout: [do1 | do2 | di1 | di2]; hist array a -> offset {0, 2M, M, 3M}
__global__ __launch_bounds__(256) void hist_reduce(
    const unsigned int* __restrict__ part, int* __restrict__ deg, int M, int nchunks)
{
    int i = blockIdx.x * blockDim.x + threadIdx.x;   // (a, c, pair)
    int n = i % HHALF;
    int ac = i / HHALF;
    int c = ac % nchunks, a = ac / nchunks;
    if (a >= 4) return;
    int node = c * HCHUNK + 2 * n;
    if (node >= M) return;
    const unsigned int* p = part + ((size_t)(a * nchunks + c) * HSLICES) * HHALF + n;
    unsigned int slo = 0, shi = 0;
#pragma unroll
    for (int s = 0; s < HSLICES; ++s) {
        unsigned int v = p[(size_t)s * HHALF];
        slo += v & 0xffffu;
        shi += v >> 16;
    }
    int abase = (a == 0) ? 0 : (a == 1) ? 2 * M : (a == 2) ? M : 3 * M;
    deg[abase + node] = (int)slo;
    if (node + 1 < M) deg[abase + node + 1] = (int)shi;
}

// ---- hierarchical exclusive scan (length N) -> rowptr (+ cursor) ----------
__global__ void scan_block_sums(const int* __restrict__ deg, int* __restrict__ partials, int N)
{
    __shared__ int sd[256];
    int base = blockIdx.x * SCAN_CHUNK + threadIdx.x * 4;
    int s = 0;
#pragma unroll
    for (int j = 0; j < 4; ++j) { int i = base + j; if (i < N) s += deg[i]; }
    sd[threadIdx.x] = s;
    __syncthreads();
    for (int off = 128; off > 0; off >>= 1) {
        if (threadIdx.x < off) sd[threadIdx.x] += sd[threadIdx.x + off];
        __syncthreads();
    }
    if (threadIdx.x == 0) partials[blockIdx.x] = sd[0];
}

__global__ void scan_partials(const int* __restrict__ partials, int* __restrict__ blockoff, int P)
{
    __shared__ int sd[256];
    int v = threadIdx.x < P ? partials[threadIdx.x] : 0;
    sd[threadIdx.x] = v;
    __syncthreads();
    for (int off = 1; off < 256; off <<= 1) {
        int t = threadIdx.x >= off ? sd[threadIdx.x - off] : 0;
        __syncthreads();
        sd[threadIdx.x] += t;
        __syncthreads();
    }
    if (threadIdx.x < P) blockoff[threadIdx.x] = sd[threadIdx.x] - v;  // exclusive
}

__global__ void scan_write(const int* __restrict__ deg, const int* __restrict__ blockoff,
                           int* __restrict__ rowptr, int* __restrict__ cursor, int N)
{
    __shared__ int sd[256];
    int base = blockIdx.x * SCAN_CHUNK + threadIdx.x * 4;
    int d0 = 0, d1 = 0, d2 = 0, d3 = 0;
    if (base + 0 < N) d0 = deg[base + 0];
    if (base + 1 < N) d1 = deg[base + 1];
    if (base + 2 < N) d2 = deg[base + 2];
    if (base + 3 < N) d3 = deg[base + 3];
    int tot = d0 + d1 + d2 + d3;
    sd[threadIdx.x] = tot;
    __syncthreads();
    for (int off = 1; off < 256; off <<= 1) {
        int t = threadIdx.x >= off ? sd[threadIdx.x - off] : 0;
        __syncthreads();
        sd[threadIdx.x] += t;
        __syncthreads();
    }
    int texcl = sd[threadIdx.x] - tot + blockoff[blockIdx.x];
    int p0 = texcl + d0, p1 = p0 + d1, p2 = p1 + d2, p3 = p2 + d3;
    if (base + 0 < N) { rowptr[base + 1] = p0; cursor[base + 0] = texcl; }
    if (base + 1 < N) { rowptr[base + 2] = p1; cursor[base + 1] = p0; }
    if (base + 2 < N) { rowptr[base + 3] = p2; cursor[base + 2] = p1; }
    if (base + 3 < N) { rowptr[base + 4] = p3; cursor[base + 3] = p2; }
    if (blockIdx.x == 0 && threadIdx.x == 0) rowptr[0] = 0;
}

// ---- CSR fill, both graphs in one dispatch (2E threads) -------------------
__global__ void csr_fill_both(
    const int* __restrict__ src1, const int* __restrict__ dst1,
    const int* __restrict__ src2, const int* __restrict__ dst2,
    int* __restrict__ cursor, int* __restrict__ colidx, int E, int M)
{
    int t = blockIdx.x * blockDim.x + threadIdx.x;
    if (t >= 2 * E) return;
    int s, ci;
    if (t < E) { ci = dst1[t];         s = src1[t]; }
    else       { ci = dst2[t - E] + M; s = src2[t - E]; }
    int pos = atomicAdd(&cursor[ci], 1);
    colidx[pos] = s;
}

// ---- W pre-swizzle into MFMA B-fragment order (bf16) ----------------------
__global__ void wswz_kernel(const float* __restrict__ W, unsigned short* __restrict__ Wz)
{
    int i = blockIdx.x * 256 + threadIdx.x;     // 0..16383
    int j = i & 7, l = (i >> 3) & 63, s = (i >> 9) & 3, t = i >> 11;
    int k = s * 32 + ((l >> 4) * 8) + j;
    int n = t * 16 + (l & 15);
    Wz[i] = f2bf(W[k * 128 + n]);
}

// ---- fused elementwise + bf16 MFMA GEMM: Yh = f(X) @ W --------------------
__global__ __launch_bounds__(256) void mfma_gemm(
    const float* __restrict__ X, const unsigned short* __restrict__ Wz,
    const int* __restrict__ deg_out, const int* __restrict__ deg_in,
    const float* __restrict__ bias, unsigned short* __restrict__ Yh,
    int M, int fuse)
{
    __shared__ __align__(16) unsigned short Abf[64 * 136];
    const int tid  = threadIdx.x;
    const int row0 = blockIdx.x * 64;

#pragma unroll
    for (int i = 0; i < 8; ++i) {
        int idx = tid + i * 256;
        int r = idx >> 5, c4 = idx & 31;
        int gr = row0 + r;
        float4 v = make_float4(0.f, 0.f, 0.f, 0.f);
        if (gr < M) {
            v = ((const float4*)X)[(size_t)gr * 32 + c4];
            if (fuse) {
                float si = rsqrtf(fmaxf((float)deg_in[gr], 1.f));
                float4 bv = ((const float4*)bias)[c4];
                v.x = fmaxf(v.x * si + bv.x, 0.f);
                v.y = fmaxf(v.y * si + bv.y, 0.f);
                v.z = fmaxf(v.z * si + bv.z, 0.f);
                v.w = fmaxf(v.w * si + bv.w, 0.f);
            }
            float so = rsqrtf(fmaxf((float)deg_out[gr], 1.f));
            v.x *= so; v.y *= so; v.z *= so; v.w *= so;
        }
        unsigned int lo = (unsigned int)f2bf(v.x) | ((unsigned int)f2bf(v.y) << 16);
        unsigned int hi = (unsigned int)f2bf(v.z) | ((unsigned int)f2bf(v.w) << 16);
        *(uint2*)(Abf + r * 136 + c4 * 4) = make_uint2(lo, hi);
    }
    __syncthreads();

    const int w = tid >> 6, lane = tid & 63;
    const int m = lane & 15, quad = lane >> 4;

    bf16x8 a[4];
#pragma unroll
    for (int s = 0; s < 4; ++s)
        a[s] = *(const bf16x8*)(Abf + (w * 16 + m) * 136 + s * 32 + quad * 8);

#pragma unroll
    for (int t = 0; t < 8; ++t) {
        f32x4 acc = {0.f, 0.f, 0.f, 0.f};
#pragma unroll
        for (int s = 0; s < 4; ++s) {
            bf16x8 b = *(const bf16x8*)(Wz + (((t * 4 + s) * 64 + lane) << 3));
            acc = __builtin_amdgcn_mfma_f32_16x16x32_bf16(a[s], b, acc, 0, 0, 0);
        }
        int gr  = row0 + w * 16 + quad * 4;
        int col = t * 16 + m;
#pragma unroll
        for (int r = 0; r < 4; ++r) {
            if (gr + r < M) Yh[(size_t)(gr + r) * 128 + col] = f2bf(acc[r]);
        }
    }
}

// ---- gather SpMM (bf16 Y) -> f32 AGG (layer 1) ----------------------------
__global__ __launch_bounds__(256) void gather_spmm(
    const uint2* __restrict__ Yv, const int* __restrict__ rowptr,
    const int* __restrict__ colidx, float4* __restrict__ AGGv, int M)
{
    int t = blockIdx.x * blockDim.x + threadIdx.x;
    int node = t >> 5, lane = t & 31;
    if (node >= M) return;
    int e   = rowptr[node];
    int end = rowptr[node + 1];
    float ax = 0.f, ay = 0.f, az = 0.f, aw = 0.f;
    for (; e + 4 <= end; e += 4) {
        int s0 = colidx[e], s1 = colidx[e + 1], s2 = colidx[e + 2], s3 = colidx[e + 3];
        uint2 v0 = Yv[(size_t)s0 * 32 + lane];
        uint2 v1 = Yv[(size_t)s1 * 32 + lane];
        uint2 v2 = Yv[(size_t)s2 * 32 + lane];
        uint2 v3 = Yv[(size_t)s3 * 32 + lane];
        ax += bflo(v0.x) + bflo(v1.x) + bflo(v2.x) + bflo(v3.x);
        ay += bfhi(v0.x) + bfhi(v1.x) + bfhi(v2.x) + bfhi(v3.x);
        az += bflo(v0.y) + bflo(v1.y) + bflo(v2.y) + bflo(v3.y);
        aw += bfhi(v0.y) + bfhi(v1.y) + bfhi(v2.y) + bfhi(v3.y);
    }
    for (; e < end; ++e) {
        int s = colidx[e];
        uint2 v = Yv[(size_t)s * 32 + lane];
        ax += bflo(v.x); ay += bfhi(v.x); az += bflo(v.y); aw += bfhi(v.y);
    }
    AGGv[(size_t)node * 32 + lane] = make_float4(ax, ay, az, aw);
}

// ---- layer-2 gather fused with finalize + column partial stats ------------
// Z[node] = gather(Yh)*rsqrt(deg_in)+b2; per-block col sums -> gpart (no atomics)
__global__ __launch_bounds__(256) void gather_stats(
    const uint2* __restrict__ Yv, const int* __restrict__ rowptr,
    const int* __restrict__ colidx, const int* __restrict__ deg_in,
    const float* __restrict__ bias, float4* __restrict__ Z,
    float* __restrict__ gpart_s, float* __restrict__ gpart_s2, int M, int NB)
{
    __shared__ float sbuf[1024], s2buf[1024];
    int t = blockIdx.x * blockDim.x + threadIdx.x;
    int node = t >> 5, lane = t & 31;
    float hx = 0.f, hy = 0.f, hz = 0.f, hw = 0.f;
    if (node < M) {
        int e   = rowptr[node];
        int end = rowptr[node + 1];
        float ax = 0.f, ay = 0.f, az = 0.f, aw = 0.f;
        for (; e + 4 <= end; e += 4) {
            int s0 = colidx[e], s1 = colidx[e + 1], s2 = colidx[e + 2], s3 = colidx[e + 3];
            uint2 v0 = Yv[(size_t)s0 * 32 + lane];
            uint2 v1 = Yv[(size_t)s1 * 32 + lane];
            uint2 v2 = Yv[(size_t)s2 * 32 + lane];
            uint2 v3 = Yv[(size_t)s3 * 32 + lane];
            ax += bflo(v0.x) + bflo(v1.x) + bflo(v2.x) + bflo(v3.x);
            ay += bfhi(v0.x) + bfhi(v1.x) + bfhi(v2.x) + bfhi(v3.x);
            az += bflo(v0.y) + bflo(v1.y) + bflo(v2.y) + bflo(v3.y);
            aw += bfhi(v0.y) + bfhi(v1.y) + bfhi(v2.y) + bfhi(v3.y);
        }
        for (; e < end; ++e) {
            int s = colidx[e];
            uint2 v = Yv[(size_t)s * 32 + lane];
            ax += bflo(v.x); ay += bfhi(v.x); az += bflo(v.y); aw += bfhi(v.y);
        }
        float si = rsqrtf(fmaxf((float)deg_in[node], 1.f));
        float4 bv = ((const float4*)bias)[lane];
        hx = ax * si + bv.x; hy = ay * si + bv.y;
        hz = az * si + bv.z; hw = aw * si + bv.w;
        Z[(size_t)node * 32 + lane] = make_float4(hx, hy, hz, hw);
    }
    int tid = threadIdx.x;
    sbuf[tid * 4 + 0] = hx;  s2buf[tid * 4 + 0] = hx * hx;
    sbuf[tid * 4 + 1] = hy;  s2buf[tid * 4 + 1] = hy * hy;
    sbuf[tid * 4 + 2] = hz;  s2buf[tid * 4 + 2] = hz * hz;
    sbuf[tid * 4 + 3] = hw;  s2buf[tid * 4 + 3] = hw * hw;
    __syncthreads();
    if (tid < 128) {   // column tid: sum over the block's 8 nodes
        float s = 0.f, s2 = 0.f;
#pragma unroll
        for (int n = 0; n < 8; ++n) { s += sbuf[n * 128 + tid]; s2 += s2buf[n * 128 + tid]; }
        gpart_s [(size_t)tid * NB + blockIdx.x] = s;
        gpart_s2[(size_t)tid * NB + blockIdx.x] = s2;
    }
}

// ---- reduce per-block partials -> mean / inv-std (ddof=1) -----------------
__global__ __launch_bounds__(256) void meanstd_reduce(
    const float* __restrict__ gpart_s, const float* __restrict__ gpart_s2,
    int NB, int M, float* __restrict__ mean, float* __restrict__ istd)
{
    __shared__ double sd[256], sd2[256];
    int c = blockIdx.x;
    double s = 0.0, s2 = 0.0;
    for (int b = threadIdx.x; b < NB; b += 256) {
        s  += (double)gpart_s [(size_t)c * NB + b];
        s2 += (double)gpart_s2[(size_t)c * NB + b];
    }
    sd[threadIdx.x] = s; sd2[threadIdx.x] = s2;
    __syncthreads();
    for (int off = 128; off > 0; off >>= 1) {
        if (threadIdx.x < off) {
            sd[threadIdx.x]  += sd[threadIdx.x + off];
            sd2[threadIdx.x] += sd2[threadIdx.x + off];
        }
        __syncthreads();
    }
    if (threadIdx.x == 0) {
        double mu  = sd[0] / (double)M;
        double var = (sd2[0] - sd[0] * mu) / (double)(M - 1);
        mean[c] = (float)mu;
        istd[c] = (float)(1.0 / sqrt(var));
    }
}

__global__ __launch_bounds__(256) void normalize_kernel(
    float* __restrict__ Z, const float* __restrict__ mean,
    const float* __restrict__ istd, int n4)
{
    int i = blockIdx.x * blockDim.x + threadIdx.x;
    if (i >= n4) return;
    float4 v = ((float4*)Z)[i];
    int c4 = (i & 31) << 2;
    v.x = (v.x - mean[c4 + 0]) * istd[c4 + 0];
    v.y = (v.y - mean[c4 + 1]) * istd[c4 + 1];
    v.z = (v.z - mean[c4 + 2]) * istd[c4 + 2];
    v.w = (v.w - mean[c4 + 3]) * istd[c4 + 3];
    ((float4*)Z)[i] = v;
}

// ---------------------------------------------------------------------------
extern "C" void kernel_launch(void* const* d_in, const int* in_sizes, int n_in,
                              void* d_out, int out_size, void* d_ws, size_t ws_size,
                              hipStream_t stream)
{
    const float* feat1 = (const float*)d_in[0];
    const float* feat2 = (const float*)d_in[1];
    const float* W1    = (const float*)d_in[2];
    const float* b1    = (const float*)d_in[3];
    const float* W2    = (const float*)d_in[4];
    const float* b2    = (const float*)d_in[5];
    const int*   src1  = (const int*)d_in[6];
    const int*   dst1  = (const int*)d_in[7];
    const int*   src2  = (const int*)d_in[8];
    const int*   dst2  = (const int*)d_in[9];
    float* out = (float*)d_out;

    const int M = in_sizes[0] / 128;   // 100000
    const int E = in_sizes[6];         // 800000
    const int N2 = 2 * M;

    // workspace carve-up
    float*  AGG  = (float*)d_ws;                                    // M*128 f32 (51.2 MB)
    unsigned short* Yh = (unsigned short*)(AGG + (size_t)M * 128);  // M*128 bf16
    unsigned short* Wz = Yh + (size_t)M * 128;                      // 2*16384 bf16
    float*  mean = (float*)(Wz + 32768);                            // 128
    float*  istd = mean + 128;                                      // 128
    int*    deg  = (int*)(istd + 128);                              // 4*M  [do1|do2|di1|di2]
    int*  rowptr = deg + (size_t)4 * M;                             // 2M+1
    int*  cursor = rowptr + (N2 + 1);                               // 2M
    int*  colidx = cursor + N2;                                     // 2E
    int*  spart  = colidx + 2 * E;                                  // 256
    int*  blockoff = spart + 256;                                   // 256

    unsigned short* Wz1 = Wz;
    unsigned short* Wz2 = Wz + 16384;

    // overlays on AGG (dead at those points in the stream):
    unsigned int* hpart = (unsigned int*)AGG;       // 4*nchunks*HSLICES*HHALF u32 = 12.8 MB
    const int NB = (M * 32 + 255) / 256;            // 12500 gather blocks
    float* gpart_s  = (float*)AGG;                  // 128*NB f32
    float* gpart_s2 = gpart_s + (size_t)128 * NB;   // 128*NB f32  (total 12.8 MB)

    const int BLK = 256;
    const int gemm_blocks = (M + 63) / 64;
    const int P2 = (N2 + SCAN_CHUNK - 1) / SCAN_CHUNK;   // 196 <= 256
    const int nchunks = (M + HCHUNK - 1) / HCHUNK;       // 5
    const int hist_blocks = 4 * nchunks * HSLICES;       // 320
    const int hr_total = 4 * nchunks * HHALF;            // 200000

    // degrees (packed-u16 LDS histogram) + weight swizzle
    hist_kernel<<<hist_blocks, BLK, 0, stream>>>(src1, dst1, src2, dst2, hpart, E, nchunks);
    hist_reduce<<<(hr_total + BLK - 1) / BLK, BLK, 0, stream>>>(hpart, deg, M, nchunks);
    wswz_kernel<<<64, BLK, 0, stream>>>(W1, Wz1);
    wswz_kernel<<<64, BLK, 0, stream>>>(W2, Wz2);

    // unified CSR build over [di1|di2] (2M nodes, 2E edges)
    int* di = deg + N2;   // [di1|di2]
    scan_block_sums<<<P2, BLK, 0, stream>>>(di, spart, N2);
    scan_partials<<<1, BLK, 0, stream>>>(spart, blockoff, P2);
    scan_write<<<P2, BLK, 0, stream>>>(di, blockoff, rowptr, cursor, N2);
    csr_fill_both<<<(2 * E + BLK - 1) / BLK, BLK, 0, stream>>>(
        src1, dst1, src2, dst2, cursor, colidx, E, M);

    for (int g = 0; g < 2; ++g) {
        const float* feat = g == 0 ? feat1 : feat2;
        const int* dgo = deg + (size_t)g * M;        // out-degrees
        const int* dgi = deg + N2 + (size_t)g * M;   // in-degrees
        const int* rp  = rowptr + (size_t)g * M;
        float* Zg = out + (size_t)g * M * 128;

        // ---- layer 1 ----
        mfma_gemm<<<gemm_blocks, BLK, 0, stream>>>(feat, Wz1, dgo, nullptr, nullptr, Yh, M, 0);
        gather_spmm<<<NB, BLK, 0, stream>>>(
            (const uint2*)Yh, rp, colidx, (float4*)AGG, M);

        // ---- layer 2 ----
        mfma_gemm<<<gemm_blocks, BLK, 0, stream>>>(AGG, Wz2, dgo, dgi, b1, Yh, M, 1);
        gather_stats<<<NB, BLK, 0, stream>>>(
            (const uint2*)Yh, rp, colidx, dgi, b2, (float4*)Zg,
            gpart_s, gpart_s2, M, NB);

        // ---- stats reduce + z-score ----
        meanstd_reduce<<<128, BLK, 0, stream>>>(gpart_s, gpart_s2, NB, M, mean, istd);
        normalize_kernel<<<(M * 32 + BLK - 1) / BLK, BLK, 0, stream>>>(Zg, mean, istd, M * 32);
    }
}